// Round 1
// baseline (1193.569 us; speedup 1.0000x reference)
//
#include <hip/hip_runtime.h>
#include <hip/hip_bf16.h>

#define B_SZ 2
#define L_SZ 4096
#define DM 768
#define DSt 16
#define E_SZ 1536
#define M_SZ (B_SZ*L_SZ)      /* 8192 rows */
#define NXD 800               /* 768 xs | 16 ds | 16 dt_pre */
#define LN_EPSF 1e-5f

// ---------------- concat [W_xp | W_dt] and [b_xp | b_dt] ----------------
__global__ void concat_wb_kernel(const float* __restrict__ W_xp, const float* __restrict__ b_xp,
                                 const float* __restrict__ W_dt, const float* __restrict__ b_dt,
                                 float* __restrict__ Wc, float* __restrict__ bc) {
  const int total = E_SZ * NXD;
  for (int idx = blockIdx.x * 256 + threadIdx.x; idx < total + NXD; idx += gridDim.x * 256) {
    if (idx < total) {
      int r = idx / NXD, c = idx % NXD;
      Wc[idx] = (c < 784) ? W_xp[r * 784 + c] : W_dt[r * 16 + (c - 784)];
    } else {
      int c = idx - total;
      bc[c] = (c < 784) ? b_xp[c] : b_dt[c - 784];
    }
  }
}

// ---------------- LayerNorm ----------------
__global__ void ln_kernel(const float* __restrict__ x, const float* __restrict__ g,
                          const float* __restrict__ beta, float* __restrict__ xn) {
  int m = blockIdx.x;
  const float* row = x + (size_t)m * DM;
  float s = 0.f, ss = 0.f;
  for (int i = threadIdx.x; i < DM; i += 256) {
    float v = row[i];
    s += v; ss += v * v;
  }
  for (int d = 32; d; d >>= 1) { s += __shfl_down(s, d); ss += __shfl_down(ss, d); }
  __shared__ float red0[4], red1[4];
  int wid = threadIdx.x >> 6;
  if ((threadIdx.x & 63) == 0) { red0[wid] = s; red1[wid] = ss; }
  __syncthreads();
  __shared__ float sh_mu, sh_inv;
  if (threadIdx.x == 0) {
    s  = red0[0] + red0[1] + red0[2] + red0[3];
    ss = red1[0] + red1[1] + red1[2] + red1[3];
    float mu = s * (1.f / DM);
    float var = ss * (1.f / DM) - mu * mu;
    sh_mu = mu;
    sh_inv = rsqrtf(var + LN_EPSF);
  }
  __syncthreads();
  float mu = sh_mu, inv = sh_inv;
  float* orow = xn + (size_t)m * DM;
  for (int i = threadIdx.x; i < DM; i += 256) {
    orow[i] = (row[i] - mu) * inv * g[i] + beta[i];
  }
}

// ---------------- generic fp32 tiled GEMM: C = A@W + bias ----------------
// A: [M x K] (row major, lda). Optional split: for k >= ksplit read A2 (lda2), same k index.
// W: [K x N] (row major, ldw). C: [M x N] (ldc). M multiple of 64, K multiple of 16.
#define BM 64
#define BN 64
#define BK 16
__global__ __launch_bounds__(256)
void gemm_kernel(const float* __restrict__ A, int lda,
                 const float* __restrict__ A2, int lda2, int ksplit,
                 const float* __restrict__ W, int ldw,
                 const float* __restrict__ bias,
                 float* __restrict__ C, int ldc,
                 int N, int K) {
  __shared__ float As[BK][BM + 4];
  __shared__ float Bs[BK][BN + 4];
  int tid = threadIdx.x;
  int tx = tid & 15, ty = tid >> 4;
  int m0 = blockIdx.y * BM;
  int n0 = blockIdx.x * BN;
  float acc[4][4] = {};
  for (int k0 = 0; k0 < K; k0 += BK) {
    const float* Ap; int ldA;
    if (A2 != nullptr && k0 >= ksplit) { Ap = A2; ldA = lda2; } else { Ap = A; ldA = lda; }
    {
      int k = tid & 15;
      int mb = tid >> 4;
#pragma unroll
      for (int r = 0; r < 4; ++r) {
        int m = mb + 16 * r;
        As[k][m] = Ap[(size_t)(m0 + m) * ldA + (k0 + k)];
      }
    }
    {
      int n = tid & 63;
      int kb = tid >> 6;
#pragma unroll
      for (int r = 0; r < 4; ++r) {
        int k = kb + 4 * r;
        int nn = n0 + n;
        Bs[k][n] = (nn < N) ? W[(size_t)(k0 + k) * ldw + nn] : 0.f;
      }
    }
    __syncthreads();
#pragma unroll
    for (int kk = 0; kk < BK; ++kk) {
      float4 a4 = *reinterpret_cast<const float4*>(&As[kk][ty * 4]);
      float4 b4 = *reinterpret_cast<const float4*>(&Bs[kk][tx * 4]);
      float a[4] = {a4.x, a4.y, a4.z, a4.w};
      float b[4] = {b4.x, b4.y, b4.z, b4.w};
#pragma unroll
      for (int i = 0; i < 4; ++i)
#pragma unroll
        for (int j = 0; j < 4; ++j)
          acc[i][j] = fmaf(a[i], b[j], acc[i][j]);
    }
    __syncthreads();
  }
#pragma unroll
  for (int i = 0; i < 4; ++i) {
    int m = m0 + ty * 4 + i;
#pragma unroll
    for (int j = 0; j < 4; ++j) {
      int n = n0 + tx * 4 + j;
      if (n < N) C[(size_t)m * ldc + n] = acc[i][j] + bias[n];
    }
  }
}

// ---------------- depthwise causal conv (4 taps) + silu ----------------
__global__ void conv_silu_kernel(const float* __restrict__ x_in, const float* __restrict__ Wc,
                                 const float* __restrict__ bc, float* __restrict__ x_act) {
  const int total = M_SZ * E_SZ;
  for (int idx = blockIdx.x * 256 + threadIdx.x; idx < total; idx += gridDim.x * 256) {
    int e = idx % E_SZ;
    int m = idx / E_SZ;
    int t = m % L_SZ;
    const float* base = x_in + (size_t)m * E_SZ + e;
    float w0 = Wc[e * 4 + 0], w1 = Wc[e * 4 + 1], w2 = Wc[e * 4 + 2], w3 = Wc[e * 4 + 3];
    float acc = bc[e] + base[0] * w3;
    if (t >= 1) acc += base[-(int)E_SZ] * w2;
    if (t >= 2) acc += base[-2 * (int)E_SZ] * w1;
    if (t >= 3) acc += base[-3 * (int)E_SZ] * w0;
    float sg = 1.f / (1.f + expf(-acc));
    x_act[idx] = acc * sg;
  }
}

// ---------------- dt / a / bterm ----------------
__global__ void post_kernel(const float* __restrict__ xd, float* __restrict__ dt_a,
                            float* __restrict__ a_a, float* __restrict__ bt_a) {
  int idx = blockIdx.x * 256 + threadIdx.x;
  if (idx >= M_SZ * DSt) return;
  int m = idx >> 4, s = idx & 15;
  float pre = xd[(size_t)m * NXD + 784 + s];
  float dsv = xd[(size_t)m * NXD + 768 + s];
  float dt = (pre > 20.f) ? pre : log1pf(expf(pre));
  dt_a[idx] = dt;
  a_a[idx] = expf(-dt);
  bt_a[idx] = dsv * expf(-0.5f * dt);
}

// ---------------- chunked scan: one wave (64 lanes) per (b, s) chain ----------------
__global__ void scan_kernel(const float* __restrict__ a_a, const float* __restrict__ bt_a,
                            float* __restrict__ v_a) {
  int chain = blockIdx.x;            // 0..31
  int b = chain >> 4, s = chain & 15;
  int lane = threadIdx.x;            // 0..63, chunk index
  const int CS = L_SZ / 64;          // 64
  size_t base = ((size_t)b * L_SZ + (size_t)lane * CS) * DSt + s;
  float A = 1.f, Bc = 0.f;
  for (int i = 0; i < CS; ++i) {
    float at = a_a[base + (size_t)i * DSt];
    float bt = bt_a[base + (size_t)i * DSt];
    Bc = fmaf(at, Bc, bt);
    A *= at;
  }
  // inclusive wave scan of affine maps (A,B): composition new = cur o prev
  for (int d = 1; d < 64; d <<= 1) {
    float Ao = __shfl_up(A, d);
    float Bo = __shfl_up(Bc, d);
    if (lane >= d) { Bc = fmaf(A, Bo, Bc); A *= Ao; }
  }
  float P = __shfl_up(Bc, 1);
  if (lane == 0) P = 0.f;
  float v = P;
  for (int i = 0; i < CS; ++i) {
    float at = a_a[base + (size_t)i * DSt];
    float bt = bt_a[base + (size_t)i * DSt];
    v = fmaf(at, v, bt);
    v_a[base + (size_t)i * DSt] = v;
  }
}

// ---------------- us + skinny GEMM (K=16) + xs add -> y1 ----------------
__global__ void us_y1_kernel(const float* __restrict__ xd, const float* __restrict__ dt_a,
                             const float* __restrict__ bt_a, const float* __restrict__ v_a,
                             const float* __restrict__ W_us, const float* __restrict__ b_us,
                             float* __restrict__ y1) {
  int m = blockIdx.x;
  int t = m % L_SZ;
  __shared__ float us_sh[DSt];
  if (threadIdx.x < DSt) {
    int s = threadIdx.x;
    float dt = dt_a[m * DSt + s];
    float v  = v_a[m * DSt + s];
    float bt = bt_a[m * DSt + s];
    float kk = (float)(L_SZ - 1 - t);
    float e1 = expf(-kk * dt);
    float em = expm1f(-kk * dt);
    float den = expm1f(-dt);
    if (den > -1e-30f) den = -1e-30f;
    us_sh[s] = e1 * v + bt * em / den;
  }
  __syncthreads();
  for (int n = threadIdx.x; n < DM; n += 256) {
    float acc = xd[(size_t)m * NXD + n] + b_us[n];
#pragma unroll
    for (int k = 0; k < DSt; ++k)
      acc = fmaf(us_sh[k], W_us[k * DM + n], acc);
    y1[(size_t)m * DM + n] = acc;
  }
}

// ---------------- launch ----------------
extern "C" void kernel_launch(void* const* d_in, const int* in_sizes, int n_in,
                              void* d_out, int out_size, void* d_ws, size_t ws_size,
                              hipStream_t stream) {
  const float* x      = (const float*)d_in[0];
  const float* ln_g   = (const float*)d_in[1];
  const float* ln_b   = (const float*)d_in[2];
  const float* W_in   = (const float*)d_in[3];
  const float* b_in   = (const float*)d_in[4];
  const float* W_conv = (const float*)d_in[5];
  const float* b_conv = (const float*)d_in[6];
  const float* W_xp   = (const float*)d_in[7];
  const float* b_xp   = (const float*)d_in[8];
  const float* W_dt   = (const float*)d_in[9];
  const float* b_dt   = (const float*)d_in[10];
  const float* W_us   = (const float*)d_in[11];
  const float* b_us   = (const float*)d_in[12];
  const float* W_out  = (const float*)d_in[13];
  const float* b_out  = (const float*)d_in[14];
  float* out = (float*)d_out;

  float* ws = (float*)d_ws;
  size_t off = 0;
  auto alloc = [&](size_t n) { float* p = ws + off; off += (n + 63) & ~(size_t)63; return p; };
  float* xn    = alloc((size_t)M_SZ * DM);      // 6.29M
  float* x_in  = alloc((size_t)M_SZ * E_SZ);    // 12.6M
  float* x_act = alloc((size_t)M_SZ * E_SZ);    // 12.6M
  float* xd    = alloc((size_t)M_SZ * NXD);     // 6.55M
  float* y1    = alloc((size_t)M_SZ * DM);      // 6.29M
  float* Wcat  = alloc((size_t)E_SZ * NXD);     // 1.23M
  float* bcat  = alloc(NXD);
  float* dt_a  = alloc((size_t)M_SZ * DSt);
  float* a_a   = alloc((size_t)M_SZ * DSt);
  float* bt_a  = alloc((size_t)M_SZ * DSt);
  float* v_a   = alloc((size_t)M_SZ * DSt);

  hipLaunchKernelGGL(concat_wb_kernel, dim3(2048), dim3(256), 0, stream,
                     W_xp, b_xp, W_dt, b_dt, Wcat, bcat);
  hipLaunchKernelGGL(ln_kernel, dim3(M_SZ), dim3(256), 0, stream, x, ln_g, ln_b, xn);
  hipLaunchKernelGGL(gemm_kernel, dim3(E_SZ / BN, M_SZ / BM), dim3(256), 0, stream,
                     xn, DM, (const float*)nullptr, 0, 1 << 30,
                     W_in, E_SZ, b_in, x_in, E_SZ, E_SZ, DM);
  hipLaunchKernelGGL(conv_silu_kernel, dim3(4096), dim3(256), 0, stream,
                     x_in, W_conv, b_conv, x_act);
  hipLaunchKernelGGL(gemm_kernel, dim3((NXD + BN - 1) / BN, M_SZ / BM), dim3(256), 0, stream,
                     x_act, E_SZ, (const float*)nullptr, 0, 1 << 30,
                     Wcat, NXD, bcat, xd, NXD, NXD, E_SZ);
  hipLaunchKernelGGL(post_kernel, dim3((M_SZ * DSt) / 256), dim3(256), 0, stream,
                     xd, dt_a, a_a, bt_a);
  hipLaunchKernelGGL(scan_kernel, dim3(B_SZ * DSt), dim3(64), 0, stream, a_a, bt_a, v_a);
  hipLaunchKernelGGL(us_y1_kernel, dim3(M_SZ), dim3(256), 0, stream,
                     xd, dt_a, bt_a, v_a, W_us, b_us, y1);
  hipLaunchKernelGGL(gemm_kernel, dim3(DM / BN, M_SZ / BM), dim3(256), 0, stream,
                     y1, DM, x_act, E_SZ, DM,
                     W_out, DM, b_out, out, DM, DM, E_SZ);
}

// Round 2
// 336.304 us; speedup vs baseline: 3.5491x; 3.5491x over previous
//
#include <hip/hip_runtime.h>
#include <hip/hip_bf16.h>
#include <hip/hip_fp16.h>

#define B_SZ 2
#define L_SZ 4096
#define DM 768
#define DSt 16
#define E_SZ 1536
#define M_SZ (B_SZ*L_SZ)      /* 8192 rows */
#define NXD 800               /* 768 xs | 16 ds | 16 dt_pre */
#define NXD_PAD 896           /* padded to 7*128 tiles */
#define LN_EPSF 1e-5f

typedef _Float16 h16;
typedef __attribute__((ext_vector_type(8))) _Float16 half8;
typedef __attribute__((ext_vector_type(4))) float f32x4;

__device__ inline void gload_lds16(const void* g, void* l) {
  __builtin_amdgcn_global_load_lds((const __attribute__((address_space(1))) unsigned int*)g,
                                   (__attribute__((address_space(3))) unsigned int*)l,
                                   16, 0, 0);
}

// ---------------- weight prep: transpose + f16 convert, concat biases ----------------
__global__ void wprep_kernel(const float* __restrict__ W_in, const float* __restrict__ W_xp,
                             const float* __restrict__ W_dt, const float* __restrict__ W_out,
                             const float* __restrict__ b_xp, const float* __restrict__ b_dt,
                             h16* __restrict__ Wt_in, h16* __restrict__ Wt_cat,
                             h16* __restrict__ Wt_out, float* __restrict__ bcat) {
  const int S1 = E_SZ * DM;            // Wt_in  [1536][768]  <- W_in [768][1536]
  const int S2 = NXD_PAD * E_SZ;       // Wt_cat [896][1536]  <- W_xp/W_dt
  const int S3 = DM * E_SZ;            // Wt_out [768][1536]  <- W_out [1536][768]
  const int total = S1 + S2 + S3 + NXD;
  for (int idx = blockIdx.x * 256 + threadIdx.x; idx < total; idx += gridDim.x * 256) {
    if (idx < S1) {
      int n = idx / DM, k = idx % DM;                 // n<1536, k<768
      Wt_in[idx] = (h16)W_in[(size_t)k * E_SZ + n];
    } else if (idx < S1 + S2) {
      int t = idx - S1;
      int n = t / E_SZ, k = t % E_SZ;                 // n<896, k<1536
      float v = 0.f;
      if (n < 784)      v = W_xp[(size_t)k * 784 + n];
      else if (n < NXD) v = W_dt[(size_t)k * DSt + (n - 784)];
      Wt_cat[t] = (h16)v;
    } else if (idx < S1 + S2 + S3) {
      int t = idx - S1 - S2;
      int n = t / E_SZ, k = t % E_SZ;                 // n<768, k<1536
      Wt_out[t] = (h16)W_out[(size_t)k * DM + n];
    } else {
      int c = idx - S1 - S2 - S3;
      bcat[c] = (c < 784) ? b_xp[c] : b_dt[c - 784];
    }
  }
}

// ---------------- LayerNorm -> f16 ----------------
__global__ void ln_kernel(const float* __restrict__ x, const float* __restrict__ g,
                          const float* __restrict__ beta, h16* __restrict__ xn) {
  int m = blockIdx.x;
  const float* row = x + (size_t)m * DM;
  float s = 0.f, ss = 0.f;
  for (int i = threadIdx.x; i < DM; i += 256) {
    float v = row[i];
    s += v; ss += v * v;
  }
  for (int d = 32; d; d >>= 1) { s += __shfl_down(s, d); ss += __shfl_down(ss, d); }
  __shared__ float red0[4], red1[4];
  int wid = threadIdx.x >> 6;
  if ((threadIdx.x & 63) == 0) { red0[wid] = s; red1[wid] = ss; }
  __syncthreads();
  __shared__ float sh_mu, sh_inv;
  if (threadIdx.x == 0) {
    s  = red0[0] + red0[1] + red0[2] + red0[3];
    ss = red1[0] + red1[1] + red1[2] + red1[3];
    float mu = s * (1.f / DM);
    float var = ss * (1.f / DM) - mu * mu;
    sh_mu = mu;
    sh_inv = rsqrtf(var + LN_EPSF);
  }
  __syncthreads();
  float mu = sh_mu, inv = sh_inv;
  h16* orow = xn + (size_t)m * DM;
  for (int i = threadIdx.x; i < DM; i += 256) {
    orow[i] = (h16)((row[i] - mu) * inv * g[i] + beta[i]);
  }
}

// ---------------- f16 MFMA GEMM (m97 structure): C = A@Bt^T + bias ----------------
// A  : [M][K] f16 row-major (lda). For k >= ksplit read A2 (lda2), same k index.
// Bt : [N][K] f16 row-major (ldb)  (i.e. W^T).
// C  : [M][ldc] OutT. Cols >= Nreal masked.
template <typename OutT>
__global__ __launch_bounds__(256)
void gemm_f16(const h16* __restrict__ A, int lda,
              const h16* __restrict__ A2, int lda2, int ksplit,
              const h16* __restrict__ Bt, int ldb,
              const float* __restrict__ bias,
              OutT* __restrict__ C, int ldc,
              int Nreal, int K) {
  __shared__ h16 Ash[128][32];
  __shared__ h16 Bsh[128][32];
  int tid = threadIdx.x;
  int w = tid >> 6, l = tid & 63;
  int m0 = blockIdx.y * 128;
  int n0 = blockIdx.x * 128;
  int wr = w >> 1, wc = w & 1;
  int lrow = l >> 2;            // 0..15 within 16-row chunk
  int lcol = (l & 3) * 8;       // f16 element col within BK=32
  int fr = l & 15, fq = l >> 4;
  f32x4 acc[4][4] = {};

  for (int k0 = 0; k0 < K; k0 += 32) {
    const h16* Ap = (k0 >= ksplit) ? A2 : A;
    int ldA = (k0 >= ksplit) ? lda2 : lda;
    // stage A tile [128][32] and Bt tile [128][32]; each wave: 4 x 1KB chunks
    gload_lds16(Ap + (size_t)(m0 + 16 * w + lrow) * ldA + k0 + lcol,      &Ash[16 * w][0]);
    gload_lds16(Ap + (size_t)(m0 + 64 + 16 * w + lrow) * ldA + k0 + lcol, &Ash[64 + 16 * w][0]);
    gload_lds16(Bt + (size_t)(n0 + 16 * w + lrow) * ldb + k0 + lcol,      &Bsh[16 * w][0]);
    gload_lds16(Bt + (size_t)(n0 + 64 + 16 * w + lrow) * ldb + k0 + lcol, &Bsh[64 + 16 * w][0]);
    __syncthreads();
    half8 af[4], bf[4];
#pragma unroll
    for (int i = 0; i < 4; ++i)
      af[i] = *(const half8*)&Ash[wr * 64 + i * 16 + fr][fq * 8];
#pragma unroll
    for (int j = 0; j < 4; ++j)
      bf[j] = *(const half8*)&Bsh[wc * 64 + j * 16 + fr][fq * 8];
#pragma unroll
    for (int i = 0; i < 4; ++i)
#pragma unroll
      for (int j = 0; j < 4; ++j)
        acc[i][j] = __builtin_amdgcn_mfma_f32_16x16x32_f16(af[i], bf[j], acc[i][j], 0, 0, 0);
    __syncthreads();
  }
#pragma unroll
  for (int i = 0; i < 4; ++i) {
#pragma unroll
    for (int j = 0; j < 4; ++j) {
      int n = n0 + wc * 64 + j * 16 + fr;
      if (n < Nreal) {
        float b = bias[n];
#pragma unroll
        for (int r = 0; r < 4; ++r) {
          int m = m0 + wr * 64 + i * 16 + fq * 4 + r;
          C[(size_t)m * ldc + n] = (OutT)(acc[i][j][r] + b);
        }
      }
    }
  }
}

// ---------------- depthwise causal conv (4 taps) + silu, 8 channels/thread ----------------
__global__ void conv_silu_kernel(const h16* __restrict__ x_in, const float* __restrict__ Wc,
                                 const float* __restrict__ bc, h16* __restrict__ x_act) {
  int idx = blockIdx.x * 256 + threadIdx.x;
  const int E8 = E_SZ / 8;
  if (idx >= M_SZ * E8) return;
  int e8 = idx % E8;
  int m = idx / E8;
  int t = m % L_SZ;
  int e0 = e8 * 8;
  const h16* p0 = x_in + (size_t)m * E_SZ + e0;
  half8 r0 = *(const half8*)p0;
  half8 r1 = {}, r2 = {}, r3 = {};
  if (t >= 1) r1 = *(const half8*)(p0 - E_SZ);
  if (t >= 2) r2 = *(const half8*)(p0 - 2 * E_SZ);
  if (t >= 3) r3 = *(const half8*)(p0 - 3 * E_SZ);
  half8 out;
#pragma unroll
  for (int j = 0; j < 8; ++j) {
    int e = e0 + j;
    float4 wv = *reinterpret_cast<const float4*>(&Wc[e * 4]);
    float acc = bc[e] + (float)r0[j] * wv.w + (float)r1[j] * wv.z
              + (float)r2[j] * wv.y + (float)r3[j] * wv.x;
    float sg = 1.f / (1.f + expf(-acc));
    out[j] = (h16)(acc * sg);
  }
  *(half8*)(x_act + (size_t)m * E_SZ + e0) = out;
}

// ---------------- dt / a / bterm (fp32) ----------------
__global__ void post_kernel(const h16* __restrict__ xd, float* __restrict__ dt_a,
                            float* __restrict__ a_a, float* __restrict__ bt_a) {
  int idx = blockIdx.x * 256 + threadIdx.x;
  if (idx >= M_SZ * DSt) return;
  int m = idx >> 4, s = idx & 15;
  float pre = (float)xd[(size_t)m * NXD + 784 + s];
  float dsv = (float)xd[(size_t)m * NXD + 768 + s];
  float dt = (pre > 20.f) ? pre : log1pf(expf(pre));
  dt_a[idx] = dt;
  a_a[idx] = expf(-dt);
  bt_a[idx] = dsv * expf(-0.5f * dt);
}

// ---------------- chunked scan: one wave per (b, s) chain ----------------
__global__ void scan_kernel(const float* __restrict__ a_a, const float* __restrict__ bt_a,
                            float* __restrict__ v_a) {
  int chain = blockIdx.x;            // 0..31
  int b = chain >> 4, s = chain & 15;
  int lane = threadIdx.x;            // 0..63
  const int CS = L_SZ / 64;          // 64
  size_t base = ((size_t)b * L_SZ + (size_t)lane * CS) * DSt + s;
  float A = 1.f, Bc = 0.f;
  for (int i = 0; i < CS; ++i) {
    float at = a_a[base + (size_t)i * DSt];
    float bt = bt_a[base + (size_t)i * DSt];
    Bc = fmaf(at, Bc, bt);
    A *= at;
  }
  for (int d = 1; d < 64; d <<= 1) {
    float Ao = __shfl_up(A, d);
    float Bo = __shfl_up(Bc, d);
    if (lane >= d) { Bc = fmaf(A, Bo, Bc); A *= Ao; }
  }
  float P = __shfl_up(Bc, 1);
  if (lane == 0) P = 0.f;
  float v = P;
  for (int i = 0; i < CS; ++i) {
    float at = a_a[base + (size_t)i * DSt];
    float bt = bt_a[base + (size_t)i * DSt];
    v = fmaf(at, v, bt);
    v_a[base + (size_t)i * DSt] = v;
  }
}

// ---------------- us + skinny GEMM (K=16) + xs add -> y1 (f16) ----------------
__global__ void us_y1_kernel(const h16* __restrict__ xd, const float* __restrict__ dt_a,
                             const float* __restrict__ bt_a, const float* __restrict__ v_a,
                             const float* __restrict__ W_us, const float* __restrict__ b_us,
                             h16* __restrict__ y1) {
  int m = blockIdx.x;
  int t = m % L_SZ;
  __shared__ float us_sh[DSt];
  if (threadIdx.x < DSt) {
    int s = threadIdx.x;
    float dt = dt_a[m * DSt + s];
    float v  = v_a[m * DSt + s];
    float bt = bt_a[m * DSt + s];
    float kk = (float)(L_SZ - 1 - t);
    float e1 = expf(-kk * dt);
    float em = expm1f(-kk * dt);
    float den = expm1f(-dt);
    if (den > -1e-30f) den = -1e-30f;
    us_sh[s] = e1 * v + bt * em / den;
  }
  __syncthreads();
  for (int n = threadIdx.x; n < DM; n += 256) {
    float acc = (float)xd[(size_t)m * NXD + n] + b_us[n];
#pragma unroll
    for (int k = 0; k < DSt; ++k)
      acc = fmaf(us_sh[k], W_us[k * DM + n], acc);
    y1[(size_t)m * DM + n] = (h16)acc;
  }
}

// ---------------- launch ----------------
extern "C" void kernel_launch(void* const* d_in, const int* in_sizes, int n_in,
                              void* d_out, int out_size, void* d_ws, size_t ws_size,
                              hipStream_t stream) {
  const float* x      = (const float*)d_in[0];
  const float* ln_g   = (const float*)d_in[1];
  const float* ln_b   = (const float*)d_in[2];
  const float* W_in   = (const float*)d_in[3];
  const float* b_in   = (const float*)d_in[4];
  const float* W_conv = (const float*)d_in[5];
  const float* b_conv = (const float*)d_in[6];
  const float* W_xp   = (const float*)d_in[7];
  const float* b_xp   = (const float*)d_in[8];
  const float* W_dt   = (const float*)d_in[9];
  const float* b_dt   = (const float*)d_in[10];
  const float* W_us   = (const float*)d_in[11];
  const float* b_us   = (const float*)d_in[12];
  const float* W_out  = (const float*)d_in[13];
  const float* b_out  = (const float*)d_in[14];
  float* out = (float*)d_out;

  char* ws = (char*)d_ws;
  size_t off = 0;
  auto alloc = [&](size_t bytes) { void* p = ws + off; off = (off + bytes + 255) & ~(size_t)255; return p; };
  h16*   xn     = (h16*)alloc((size_t)M_SZ * DM * 2);
  h16*   x_in   = (h16*)alloc((size_t)M_SZ * E_SZ * 2);
  h16*   x_act  = (h16*)alloc((size_t)M_SZ * E_SZ * 2);
  h16*   xd     = (h16*)alloc((size_t)M_SZ * NXD * 2);
  h16*   y1     = (h16*)alloc((size_t)M_SZ * DM * 2);
  h16*   Wt_in  = (h16*)alloc((size_t)E_SZ * DM * 2);
  h16*   Wt_cat = (h16*)alloc((size_t)NXD_PAD * E_SZ * 2);
  h16*   Wt_out = (h16*)alloc((size_t)DM * E_SZ * 2);
  float* bcat   = (float*)alloc(NXD * 4);
  float* dt_a   = (float*)alloc((size_t)M_SZ * DSt * 4);
  float* a_a    = (float*)alloc((size_t)M_SZ * DSt * 4);
  float* bt_a   = (float*)alloc((size_t)M_SZ * DSt * 4);
  float* v_a    = (float*)alloc((size_t)M_SZ * DSt * 4);

  hipLaunchKernelGGL(wprep_kernel, dim3(8192), dim3(256), 0, stream,
                     W_in, W_xp, W_dt, W_out, b_xp, b_dt, Wt_in, Wt_cat, Wt_out, bcat);
  hipLaunchKernelGGL(ln_kernel, dim3(M_SZ), dim3(256), 0, stream, x, ln_g, ln_b, xn);
  hipLaunchKernelGGL((gemm_f16<h16>), dim3(E_SZ / 128, M_SZ / 128), dim3(256), 0, stream,
                     xn, DM, xn, DM, 1 << 30,
                     Wt_in, DM, b_in, x_in, E_SZ, E_SZ, DM);
  hipLaunchKernelGGL(conv_silu_kernel, dim3((M_SZ * E_SZ / 8) / 256), dim3(256), 0, stream,
                     x_in, W_conv, b_conv, x_act);
  hipLaunchKernelGGL((gemm_f16<h16>), dim3(NXD_PAD / 128, M_SZ / 128), dim3(256), 0, stream,
                     x_act, E_SZ, x_act, E_SZ, 1 << 30,
                     Wt_cat, E_SZ, bcat, xd, NXD, NXD, E_SZ);
  hipLaunchKernelGGL(post_kernel, dim3((M_SZ * DSt) / 256), dim3(256), 0, stream,
                     xd, dt_a, a_a, bt_a);
  hipLaunchKernelGGL(scan_kernel, dim3(B_SZ * DSt), dim3(64), 0, stream, a_a, bt_a, v_a);
  hipLaunchKernelGGL(us_y1_kernel, dim3(M_SZ), dim3(256), 0, stream,
                     xd, dt_a, bt_a, v_a, W_us, b_us, y1);
  hipLaunchKernelGGL((gemm_f16<float>), dim3(DM / 128, M_SZ / 128), dim3(256), 0, stream,
                     y1, DM, x_act, E_SZ, DM,
                     Wt_out, E_SZ, b_out, out, DM, DM, E_SZ);
}